// Round 3
// baseline (1575.422 us; speedup 1.0000x reference)
//
#include <hip/hip_runtime.h>
#include <stdint.h>

// GatedDeltaNet fused pipeline, round 3 (= round-2 source; R2 bench never ran:
// GPU acquisition timeout). ws footprint 210MB with lifetime unions, ws_size
// guard with sentinel fallback (12345.0f) to diagnose workspace-overrun.

#define B_ 2
#define T_ 2048
#define HID_ 2048
#define H_ 32
#define KVH_ 8
#define M_ (B_*T_)            // 4096 tokens
#define NQKV 6144             // q4096 | k1024 | v1024
#define NGBA 4224             // g4096 | b32 | a32 | pad64   (33*128)
#define NALL (NQKV + NGBA)    // Wallt rows
#define OFS_K 4096
#define OFS_V 5120
#define OFS_B2 4096           // within gba
#define OFS_A2 4128

typedef unsigned short u16;
typedef unsigned int u32;
typedef __attribute__((ext_vector_type(2))) float f32x2;
typedef __attribute__((ext_vector_type(4))) float f32x4;
typedef __attribute__((ext_vector_type(2))) u32 u32x2;
typedef __attribute__((ext_vector_type(8))) __bf16 bf16x8;

__device__ __forceinline__ u16 f2b(float f) {            // f32 -> bf16 RTNE
  u32 u = __builtin_bit_cast(u32, f);
  u32 r = (u + 0x7FFFu + ((u >> 16) & 1u)) >> 16;
  return (u16)r;
}
__device__ __forceinline__ float b2f(u16 x) {
  u32 u = ((u32)x) << 16;
  return __builtin_bit_cast(float, u);
}

// ---------------- sentinel fill (ws-too-small fallback diagnostic) ----------------
__global__ __launch_bounds__(256) void fill_k(float* __restrict__ p, int n, float v) {
  int i = blockIdx.x * 256 + threadIdx.x;
  if (i < n) p[i] = v;
}

// ---------------- cast hidden_states to bf16 ----------------
__global__ __launch_bounds__(256) void cast_bf16_k(const float* __restrict__ in,
                                                   u16* __restrict__ out, int n4) {
  int i = blockIdx.x * 256 + threadIdx.x;
  if (i >= n4) return;
  f32x4 v = ((const f32x4*)in)[i];
  u32x2 p;
  p.x = (u32)f2b(v.x) | ((u32)f2b(v.y) << 16);
  p.y = (u32)f2b(v.z) | ((u32)f2b(v.w) << 16);
  ((u32x2*)out)[i] = p;
}

// ---------------- transpose + cast weights: in[R][C] f32 -> out[C][R] bf16 ----------------
__global__ __launch_bounds__(256) void transpose_cast_k(const float* __restrict__ in,
                                                        u16* __restrict__ out, int R, int C) {
  __shared__ float tile[32][33];
  int bc = blockIdx.x * 32, br = blockIdx.y * 32;
  int tx = threadIdx.x & 31, ty = threadIdx.x >> 5;   // 32x8
#pragma unroll
  for (int i = ty; i < 32; i += 8) tile[i][tx] = in[(size_t)(br + i) * C + bc + tx];
  __syncthreads();
#pragma unroll
  for (int i = ty; i < 32; i += 8) out[(size_t)(bc + i) * R + br + tx] = f2b(tile[tx][i]);
}

// ---------------- bf16 NT GEMM: C[M][N] = sum_k A[m][k]*Bt[n][k] ----------------
// 128x128 tile, BK=32, 4 waves (2x2), 16x16x32 MFMA, global_load_lds width-16.
template <int OUT_BF16>
__global__ __launch_bounds__(256) void gemm_nt_k(const u16* __restrict__ A, const u16* __restrict__ Bt,
                                                 void* __restrict__ Cv, int M, int N, int K) {
  __shared__ u16 As[128 * 32];
  __shared__ u16 Bs[128 * 32];
  int tid = threadIdx.x;
  int lane = tid & 63, wid = tid >> 6;
  int wm = wid >> 1, wn = wid & 1;
  int bm = blockIdx.y << 7, bn = blockIdx.x << 7;
  int r16 = lane & 15, kp = (lane >> 4) << 3;
  f32x4 acc[4][4] = {};
  for (int k0 = 0; k0 < K; k0 += 32) {
    __syncthreads();
#pragma unroll
    for (int half = 0; half < 2; ++half) {          // stage A tile (128x32)
      int c = tid + (half << 8);
      int row = c >> 2, kc = (c & 3) << 3;
      const u16* g = A + (size_t)(bm + row) * K + k0 + kc;
      __builtin_amdgcn_global_load_lds((const __attribute__((address_space(1))) void*)g,
          (__attribute__((address_space(3))) void*)((char*)As + (size_t)((wid << 6) + (half << 8)) * 16),
          16, 0, 0);
    }
#pragma unroll
    for (int half = 0; half < 2; ++half) {          // stage B tile (128x32)
      int c = tid + (half << 8);
      int row = c >> 2, kc = (c & 3) << 3;
      const u16* g = Bt + (size_t)(bn + row) * K + k0 + kc;
      __builtin_amdgcn_global_load_lds((const __attribute__((address_space(1))) void*)g,
          (__attribute__((address_space(3))) void*)((char*)Bs + (size_t)((wid << 6) + (half << 8)) * 16),
          16, 0, 0);
    }
    asm volatile("s_waitcnt vmcnt(0)" ::: "memory");
    __syncthreads();
    bf16x8 af[4], bfv[4];
#pragma unroll
    for (int i = 0; i < 4; ++i) af[i] = *(const bf16x8*)&As[(size_t)((wm << 6) + (i << 4) + r16) * 32 + kp];
#pragma unroll
    for (int j = 0; j < 4; ++j) bfv[j] = *(const bf16x8*)&Bs[(size_t)((wn << 6) + (j << 4) + r16) * 32 + kp];
#pragma unroll
    for (int i = 0; i < 4; ++i)
#pragma unroll
      for (int j = 0; j < 4; ++j)
        acc[i][j] = __builtin_amdgcn_mfma_f32_16x16x32_bf16(af[i], bfv[j], acc[i][j], 0, 0, 0);
  }
  int rg = (lane >> 4) << 2;
#pragma unroll
  for (int i = 0; i < 4; ++i)
#pragma unroll
    for (int j = 0; j < 4; ++j)
#pragma unroll
      for (int r = 0; r < 4; ++r) {
        int row = bm + (wm << 6) + (i << 4) + rg + r;
        int col = bn + (wn << 6) + (j << 4) + r16;
        if (OUT_BF16) ((u16*)Cv)[(size_t)row * N + col] = f2b(acc[i][j][r]);
        else          ((float*)Cv)[(size_t)row * N + col] = acc[i][j][r];
      }
}

// ---------------- l2norm q,k + repack to [B][H][T][.] fp32 ; copy v ----------------
__global__ __launch_bounds__(256) void ew1_k(const u16* __restrict__ qkv,
                                             float* __restrict__ Qb, float* __restrict__ KVb) {
  const int BTH = B_ * T_ * H_;        // 131072
  const int BTKV = B_ * T_ * KVH_;     // 32768
  int row = blockIdx.x * 4 + (threadIdx.x >> 6);
  int lane = threadIdx.x & 63;
  const u16* src; float* dst; int donorm = 1; float extra = 1.0f;
  if (row < BTH) {                                  // q rows: (bt,h)
    int hh = row & 31; int bt = row >> 5;
    src = qkv + (size_t)bt * NQKV + (hh << 7);
    int b = bt >> 11, t = bt & 2047;
    dst = Qb + ((size_t)(b * H_ + hh) * T_ + t) * 128;
    extra = 0.08838834764831843f;                   // 1/sqrt(128) folded q scale
  } else if (row < BTH + BTKV) {                    // k rows
    int r2 = row - BTH; int kh = r2 & 7; int bt = r2 >> 3;
    src = qkv + (size_t)bt * NQKV + OFS_K + (kh << 7);
    int b = bt >> 11, t = bt & 2047;
    dst = KVb + ((size_t)(b * KVH_ + kh) * T_ + t) * 256;
  } else {                                          // v rows (no norm)
    int r2 = row - BTH - BTKV; int kh = r2 & 7; int bt = r2 >> 3;
    src = qkv + (size_t)bt * NQKV + OFS_V + (kh << 7);
    int b = bt >> 11, t = bt & 2047;
    dst = KVb + ((size_t)(b * KVH_ + kh) * T_ + t) * 256 + 128;
    donorm = 0;
  }
  u32 raw = ((const u32*)src)[lane];
  float x0 = b2f((u16)raw), x1 = b2f((u16)(raw >> 16));
  if (donorm) {
    float ss = x0 * x0 + x1 * x1;
    ss += __shfl_xor(ss, 1);  ss += __shfl_xor(ss, 2);  ss += __shfl_xor(ss, 4);
    ss += __shfl_xor(ss, 8);  ss += __shfl_xor(ss, 16); ss += __shfl_xor(ss, 32);
    float sc = extra / sqrtf(ss + 1e-6f);
    x0 *= sc; x1 *= sc;
  }
  f32x2 o; o.x = x0; o.y = x1;
  ((f32x2*)dst)[lane] = o;
}

// ---------------- per-(b,h,t): eg = exp(g), beta ----------------
__global__ __launch_bounds__(256) void eb_k(const u16* __restrict__ gba,
                                            const float* __restrict__ A_log,
                                            const float* __restrict__ dt_bias,
                                            f32x2* __restrict__ EB) {
  int i = blockIdx.x * 256 + threadIdx.x;          // i = bt*32 + hh  (hh in lane -> coalesced reads)
  int hh = i & 31; int bt = i >> 5;
  int t = bt & 2047, b = bt >> 11;
  const u16* rowp = gba + (size_t)bt * NGBA;
  float braw = b2f(rowp[OFS_B2 + hh]);
  float araw = b2f(rowp[OFS_A2 + hh]);
  float beta = 2.0f / (1.0f + expf(-braw));
  float x = araw + dt_bias[hh];
  float sp = (x > 20.0f) ? x : log1pf(expf(x));
  float g = -expf(A_log[hh]) * sp;
  f32x2 e; e.x = expf(g); e.y = beta;
  EB[((size_t)(b * H_ + hh)) * T_ + t] = e;
}

// ---------------- gated delta rule scan ----------------
// One 64-lane wave per (b, h, 8-dv slice).  lane = dkq(8) + 8*dvl(8).
// Lane owns S[dkq*16 .. +16)[dv0+dvl] in 4 f32x4. dk-reduce = shfl_xor 1,2,4.
// Scalar decay: k.(e^g * S) = e^g * (k.S).
struct StepB { f32x4 k[4]; f32x4 q[4]; f32x2 eb; float v; };

__global__ __launch_bounds__(64) void scan_k(const float* __restrict__ Qb, const float* __restrict__ KVb,
                                             const f32x2* __restrict__ EB, float* __restrict__ O) {
  int idx = blockIdx.x;
  int head = idx & 63, dvg = idx >> 6;      // same head -> same blockIdx%8 -> same XCD (L2 reuse)
  int b = head >> 5, hh = head & 31;
  int lane = threadIdx.x;
  int dkq = lane & 7, dvl = lane >> 3;
  int dv0 = dvg << 3;
  const f32x4* qp = (const f32x4*)(Qb + ((size_t)(b * H_ + hh) * T_) * 128) + (dkq << 2);
  const f32x4* kp = (const f32x4*)(KVb + ((size_t)(b * KVH_ + (hh >> 2)) * T_) * 256) + (dkq << 2);
  const float* vp = KVb + ((size_t)(b * KVH_ + (hh >> 2)) * T_) * 256 + 128 + dv0 + dvl;
  const f32x2* ep = EB + (size_t)(b * H_ + hh) * T_;
  float* op = O + (size_t)b * T_ * H_ * 128 + hh * 128 + dv0 + dvl;

  f32x4 S[4] = {};
  StepB s[4];
#pragma unroll
  for (int j = 0; j < 4; ++j) {
#pragma unroll
    for (int c = 0; c < 4; ++c) { s[j].k[c] = kp[j * 64 + c]; s[j].q[c] = qp[j * 32 + c]; }
    s[j].v = vp[(size_t)j * 256]; s[j].eb = ep[j];
  }
  for (int t = 0; t < T_; t += 4) {
#pragma unroll
    for (int j = 0; j < 4; ++j) {
      int tt = t + j;
      f32x4 a = s[j].k[0] * S[0] + s[j].k[1] * S[1] + s[j].k[2] * S[2] + s[j].k[3] * S[3];
      float kS = a.x + a.y + a.z + a.w;
      kS += __shfl_xor(kS, 1); kS += __shfl_xor(kS, 2); kS += __shfl_xor(kS, 4);
      float eg = s[j].eb.x, beta = s[j].eb.y;
      float vadj = (s[j].v - eg * kS) * beta;
      S[0] = S[0] * eg + s[j].k[0] * vadj;
      S[1] = S[1] * eg + s[j].k[1] * vadj;
      S[2] = S[2] * eg + s[j].k[2] * vadj;
      S[3] = S[3] * eg + s[j].k[3] * vadj;
      f32x4 ob = s[j].q[0] * S[0] + s[j].q[1] * S[1] + s[j].q[2] * S[2] + s[j].q[3] * S[3];
      float o = ob.x + ob.y + ob.z + ob.w;
      o += __shfl_xor(o, 1); o += __shfl_xor(o, 2); o += __shfl_xor(o, 4);
      if (dkq == 0) op[(size_t)tt * (H_ * 128)] = o;   // O[b][t][h][dv]
      int nt = tt + 4; if (nt >= T_) nt = T_ - 1;      // clamped tail prefetch
#pragma unroll
      for (int c = 0; c < 4; ++c) { s[j].k[c] = kp[(size_t)nt * 64 + c]; s[j].q[c] = qp[(size_t)nt * 32 + c]; }
      s[j].v = vp[(size_t)nt * 256]; s[j].eb = ep[nt];
    }
  }
}

// ---------------- rmsnorm(o)*w * gate*sigmoid(gate) -> bf16 Xo ----------------
__global__ __launch_bounds__(256) void ew2_k(const float* __restrict__ O, const u16* __restrict__ gba,
                                             const float* __restrict__ w, u16* __restrict__ Xo) {
  int r = blockIdx.x * 4 + (threadIdx.x >> 6);     // r = (b*T+t)*H + h
  int lane = threadIdx.x & 63;
  f32x2 ov = ((const f32x2*)(O + (size_t)r * 128))[lane];
  float ss = ov.x * ov.x + ov.y * ov.y;
  ss += __shfl_xor(ss, 1);  ss += __shfl_xor(ss, 2);  ss += __shfl_xor(ss, 4);
  ss += __shfl_xor(ss, 8);  ss += __shfl_xor(ss, 16); ss += __shfl_xor(ss, 32);
  float rms = 1.0f / sqrtf(ss * (1.0f / 128.0f) + 1e-5f);
  f32x2 wv = ((const f32x2*)w)[lane];
  int hh = r & 31; size_t bt = (size_t)(r >> 5);
  u32 graw = ((const u32*)(gba + bt * NGBA + (hh << 7)))[lane];
  float g0 = b2f((u16)graw), g1 = b2f((u16)(graw >> 16));
  float y0 = ov.x * rms * wv.x * (g0 / (1.0f + expf(-g0)));
  float y1 = ov.y * rms * wv.y * (g1 / (1.0f + expf(-g1)));
  u32 pk = (u32)f2b(y0) | ((u32)f2b(y1) << 16);
  ((u32*)(Xo + bt * 4096 + (hh << 7)))[lane] = pk;
}

// ---------------------------------------------------------------------------
extern "C" void kernel_launch(void* const* d_in, const int* in_sizes, int n_in,
                              void* d_out, int out_size, void* d_ws, size_t ws_size,
                              hipStream_t stream) {
  const float* h    = (const float*)d_in[0];
  const float* Wq   = (const float*)d_in[1];
  const float* Wk   = (const float*)d_in[2];
  const float* Wv   = (const float*)d_in[3];
  const float* Wb   = (const float*)d_in[4];
  const float* Wa   = (const float*)d_in[5];
  const float* Wg   = (const float*)d_in[6];
  const float* Wo   = (const float*)d_in[7];
  const float* Alog = (const float*)d_in[8];
  const float* dtb  = (const float*)d_in[9];
  const float* onw  = (const float*)d_in[10];

  // ---- workspace layout with lifetime unions (total ~210 MiB) ----
  constexpr size_t SZ_X     = (size_t)M_ * HID_ * 2;            // 16 MiB   [cast .. projGEMM]
  constexpr size_t SZ_WALLT = (size_t)NALL * HID_ * 2;          // 40.5 MiB [transpose .. projGEMM]
  constexpr size_t SZ_WOT   = (size_t)HID_ * 4096 * 2;          // 16 MiB   [.. finalGEMM]
  constexpr size_t SZ_QKV   = (size_t)M_ * NQKV * 2;            // 48 MiB   [projGEMM .. ew1]
  constexpr size_t SZ_GBA   = (size_t)M_ * NGBA * 2;            // 33 MiB   [projGEMM .. ew2]
  constexpr size_t SZ_QB    = (size_t)B_ * H_ * T_ * 128 * 4;   // 64 MiB   [ew1 .. scan]
  constexpr size_t SZ_KVB   = (size_t)B_ * KVH_ * T_ * 256 * 4; // 32 MiB   [ew1 .. scan]
  constexpr size_t SZ_EB    = (size_t)B_ * H_ * T_ * 8;         // 1 MiB    [eb .. scan]
  constexpr size_t SZ_O     = (size_t)M_ * H_ * 128 * 4;        // 64 MiB   [scan .. ew2]
  constexpr size_t SZ_U1    = SZ_QB;                            // >= SZ_X+SZ_WALLT, >= SZ_XO
  constexpr size_t SZ_U2    = SZ_O;                             // >= SZ_QKV
  constexpr size_t NEED = SZ_U1 + SZ_WOT + SZ_GBA + SZ_U2 + SZ_KVB + SZ_EB;  // 220,200,960

  if (ws_size < NEED) {   // diagnostic fallback: sentinel output, never fault
    fill_k<<<dim3((out_size + 255) / 256), dim3(256), 0, stream>>>((float*)d_out, out_size, 12345.0f);
    return;
  }

  char* base   = (char*)d_ws;
  char* segU1  = base;                    // P1-2: X @ +0, Wallt @ +SZ_X; P3-4: Qb; P5-6: Xo
  char* segWot = segU1 + SZ_U1;
  char* segGBA = segWot + SZ_WOT;
  char* segU2  = segGBA + SZ_GBA;         // P2-3: qkv; P4-5: O
  char* segKVB = segU2 + SZ_U2;
  char* segEB  = segKVB + SZ_KVB;

  u16*   X     = (u16*)segU1;
  u16*   Wallt = (u16*)(segU1 + SZ_X);
  u16*   Wot   = (u16*)segWot;
  u16*   qkv   = (u16*)segU2;
  u16*   gba   = (u16*)segGBA;
  float* Qb    = (float*)segU1;
  float* KVb   = (float*)segKVB;
  f32x2* EB    = (f32x2*)segEB;
  float* O     = (float*)segU2;
  u16*   Xo    = (u16*)segU1;

  cast_bf16_k<<<dim3(M_ * HID_ / 4 / 256), dim3(256), 0, stream>>>(h, X, M_ * HID_ / 4);

  // Wallt rows: [0,4096)=Wq^T | [4096,5120)=Wk^T | [5120,6144)=Wv^T |
  //             [6144,10240)=Wg^T | [10240,10272)=Wb^T | [10272,10304)=Wa^T | [10304,10368)=0
  transpose_cast_k<<<dim3(4096/32, 2048/32), dim3(256), 0, stream>>>(Wq, Wallt, 2048, 4096);
  transpose_cast_k<<<dim3(1024/32, 2048/32), dim3(256), 0, stream>>>(Wk, Wallt + (size_t)4096 * HID_, 2048, 1024);
  transpose_cast_k<<<dim3(1024/32, 2048/32), dim3(256), 0, stream>>>(Wv, Wallt + (size_t)5120 * HID_, 2048, 1024);
  transpose_cast_k<<<dim3(4096/32, 2048/32), dim3(256), 0, stream>>>(Wg, Wallt + (size_t)6144 * HID_, 2048, 4096);
  transpose_cast_k<<<dim3(32/32,   2048/32), dim3(256), 0, stream>>>(Wb, Wallt + (size_t)10240 * HID_, 2048, 32);
  transpose_cast_k<<<dim3(32/32,   2048/32), dim3(256), 0, stream>>>(Wa, Wallt + (size_t)10272 * HID_, 2048, 32);
  hipMemsetAsync(Wallt + (size_t)10304 * HID_, 0, (size_t)64 * HID_ * 2, stream);
  transpose_cast_k<<<dim3(2048/32, 4096/32), dim3(256), 0, stream>>>(Wo, Wot, 4096, 2048);

  // projection GEMMs (bf16 out)
  gemm_nt_k<1><<<dim3(NQKV/128, M_/128), dim3(256), 0, stream>>>(X, Wallt, qkv, M_, NQKV, HID_);
  gemm_nt_k<1><<<dim3(NGBA/128, M_/128), dim3(256), 0, stream>>>(X, Wallt + (size_t)NQKV * HID_, gba, M_, NGBA, HID_);

  ew1_k<<<dim3((B_*T_*H_ + 2*B_*T_*KVH_) / 4), dim3(256), 0, stream>>>(qkv, Qb, KVb);
  eb_k<<<dim3(B_*H_*T_ / 256), dim3(256), 0, stream>>>(gba, Alog, dtb, EB);

  scan_k<<<dim3(B_*H_ * 16), dim3(64), 0, stream>>>(Qb, KVb, EB, O);

  ew2_k<<<dim3(B_*T_*H_ / 4), dim3(256), 0, stream>>>(O, gba, onw, Xo);

  // output projection: d_out[4096][2048] = Xo @ Wo  (fp32 out)
  gemm_nt_k<0><<<dim3(2048/128, M_/128), dim3(256), 0, stream>>>(Xo, Wot, d_out, M_, 2048, 4096);
}

// Round 11
// 1524.338 us; speedup vs baseline: 1.0335x; 1.0335x over previous
//
#include <hip/hip_runtime.h>
#include <stdint.h>

// GatedDeltaNet fused pipeline, round 11 (= round-4 source; R4-R10 benches
// never ran: 7x GPU acquisition timeout, 1x container failure).
// R4 changes vs R3 (which passed, 1575us, scan_k=1032us latency-bound):
//   scan_k rewritten: quad ring-buffer prefetch (static rotation, sched_barrier
//   pinned so the compiler can't sink loads — R3's VGPR=84 showed it did),
//   kS precomputed one step ahead so the two 3-stage shfl reduce chains
//   (kS_next and o_cur) interleave. Everything else identical to R3.

#define B_ 2
#define T_ 2048
#define HID_ 2048
#define H_ 32
#define KVH_ 8
#define M_ (B_*T_)            // 4096 tokens
#define NQKV 6144             // q4096 | k1024 | v1024
#define NGBA 4224             // g4096 | b32 | a32 | pad64   (33*128)
#define NALL (NQKV + NGBA)    // Wallt rows
#define OFS_K 4096
#define OFS_V 5120
#define OFS_B2 4096           // within gba
#define OFS_A2 4128

typedef unsigned short u16;
typedef unsigned int u32;
typedef __attribute__((ext_vector_type(2))) float f32x2;
typedef __attribute__((ext_vector_type(4))) float f32x4;
typedef __attribute__((ext_vector_type(2))) u32 u32x2;
typedef __attribute__((ext_vector_type(8))) __bf16 bf16x8;

__device__ __forceinline__ u16 f2b(float f) {            // f32 -> bf16 RTNE
  u32 u = __builtin_bit_cast(u32, f);
  u32 r = (u + 0x7FFFu + ((u >> 16) & 1u)) >> 16;
  return (u16)r;
}
__device__ __forceinline__ float b2f(u16 x) {
  u32 u = ((u32)x) << 16;
  return __builtin_bit_cast(float, u);
}

// ---------------- sentinel fill (ws-too-small fallback diagnostic) ----------------
__global__ __launch_bounds__(256) void fill_k(float* __restrict__ p, int n, float v) {
  int i = blockIdx.x * 256 + threadIdx.x;
  if (i < n) p[i] = v;
}

// ---------------- cast hidden_states to bf16 ----------------
__global__ __launch_bounds__(256) void cast_bf16_k(const float* __restrict__ in,
                                                   u16* __restrict__ out, int n4) {
  int i = blockIdx.x * 256 + threadIdx.x;
  if (i >= n4) return;
  f32x4 v = ((const f32x4*)in)[i];
  u32x2 p;
  p.x = (u32)f2b(v.x) | ((u32)f2b(v.y) << 16);
  p.y = (u32)f2b(v.z) | ((u32)f2b(v.w) << 16);
  ((u32x2*)out)[i] = p;
}

// ---------------- transpose + cast weights: in[R][C] f32 -> out[C][R] bf16 ----------------
__global__ __launch_bounds__(256) void transpose_cast_k(const float* __restrict__ in,
                                                        u16* __restrict__ out, int R, int C) {
  __shared__ float tile[32][33];
  int bc = blockIdx.x * 32, br = blockIdx.y * 32;
  int tx = threadIdx.x & 31, ty = threadIdx.x >> 5;   // 32x8
#pragma unroll
  for (int i = ty; i < 32; i += 8) tile[i][tx] = in[(size_t)(br + i) * C + bc + tx];
  __syncthreads();
#pragma unroll
  for (int i = ty; i < 32; i += 8) out[(size_t)(bc + i) * R + br + tx] = f2b(tile[tx][i]);
}

// ---------------- bf16 NT GEMM: C[M][N] = sum_k A[m][k]*Bt[n][k] ----------------
// 128x128 tile, BK=32, 4 waves (2x2), 16x16x32 MFMA, global_load_lds width-16.
template <int OUT_BF16>
__global__ __launch_bounds__(256) void gemm_nt_k(const u16* __restrict__ A, const u16* __restrict__ Bt,
                                                 void* __restrict__ Cv, int M, int N, int K) {
  __shared__ u16 As[128 * 32];
  __shared__ u16 Bs[128 * 32];
  int tid = threadIdx.x;
  int lane = tid & 63, wid = tid >> 6;
  int wm = wid >> 1, wn = wid & 1;
  int bm = blockIdx.y << 7, bn = blockIdx.x << 7;
  int r16 = lane & 15, kp = (lane >> 4) << 3;
  f32x4 acc[4][4] = {};
  for (int k0 = 0; k0 < K; k0 += 32) {
    __syncthreads();
#pragma unroll
    for (int half = 0; half < 2; ++half) {          // stage A tile (128x32)
      int c = tid + (half << 8);
      int row = c >> 2, kc = (c & 3) << 3;
      const u16* g = A + (size_t)(bm + row) * K + k0 + kc;
      __builtin_amdgcn_global_load_lds((const __attribute__((address_space(1))) void*)g,
          (__attribute__((address_space(3))) void*)((char*)As + (size_t)((wid << 6) + (half << 8)) * 16),
          16, 0, 0);
    }
#pragma unroll
    for (int half = 0; half < 2; ++half) {          // stage B tile (128x32)
      int c = tid + (half << 8);
      int row = c >> 2, kc = (c & 3) << 3;
      const u16* g = Bt + (size_t)(bn + row) * K + k0 + kc;
      __builtin_amdgcn_global_load_lds((const __attribute__((address_space(1))) void*)g,
          (__attribute__((address_space(3))) void*)((char*)Bs + (size_t)((wid << 6) + (half << 8)) * 16),
          16, 0, 0);
    }
    asm volatile("s_waitcnt vmcnt(0)" ::: "memory");
    __syncthreads();
    bf16x8 af[4], bfv[4];
#pragma unroll
    for (int i = 0; i < 4; ++i) af[i] = *(const bf16x8*)&As[(size_t)((wm << 6) + (i << 4) + r16) * 32 + kp];
#pragma unroll
    for (int j = 0; j < 4; ++j) bfv[j] = *(const bf16x8*)&Bs[(size_t)((wn << 6) + (j << 4) + r16) * 32 + kp];
#pragma unroll
    for (int i = 0; i < 4; ++i)
#pragma unroll
      for (int j = 0; j < 4; ++j)
        acc[i][j] = __builtin_amdgcn_mfma_f32_16x16x32_bf16(af[i], bfv[j], acc[i][j], 0, 0, 0);
  }
  int rg = (lane >> 4) << 2;
#pragma unroll
  for (int i = 0; i < 4; ++i)
#pragma unroll
    for (int j = 0; j < 4; ++j)
#pragma unroll
      for (int r = 0; r < 4; ++r) {
        int row = bm + (wm << 6) + (i << 4) + rg + r;
        int col = bn + (wn << 6) + (j << 4) + r16;
        if (OUT_BF16) ((u16*)Cv)[(size_t)row * N + col] = f2b(acc[i][j][r]);
        else          ((float*)Cv)[(size_t)row * N + col] = acc[i][j][r];
      }
}

// ---------------- l2norm q,k + repack to [B][H][T][.] fp32 ; copy v ----------------
__global__ __launch_bounds__(256) void ew1_k(const u16* __restrict__ qkv,
                                             float* __restrict__ Qb, float* __restrict__ KVb) {
  const int BTH = B_ * T_ * H_;        // 131072
  const int BTKV = B_ * T_ * KVH_;     // 32768
  int row = blockIdx.x * 4 + (threadIdx.x >> 6);
  int lane = threadIdx.x & 63;
  const u16* src; float* dst; int donorm = 1; float extra = 1.0f;
  if (row < BTH) {                                  // q rows: (bt,h)
    int hh = row & 31; int bt = row >> 5;
    src = qkv + (size_t)bt * NQKV + (hh << 7);
    int b = bt >> 11, t = bt & 2047;
    dst = Qb + ((size_t)(b * H_ + hh) * T_ + t) * 128;
    extra = 0.08838834764831843f;                   // 1/sqrt(128) folded q scale
  } else if (row < BTH + BTKV) {                    // k rows
    int r2 = row - BTH; int kh = r2 & 7; int bt = r2 >> 3;
    src = qkv + (size_t)bt * NQKV + OFS_K + (kh << 7);
    int b = bt >> 11, t = bt & 2047;
    dst = KVb + ((size_t)(b * KVH_ + kh) * T_ + t) * 256;
  } else {                                          // v rows (no norm)
    int r2 = row - BTH - BTKV; int kh = r2 & 7; int bt = r2 >> 3;
    src = qkv + (size_t)bt * NQKV + OFS_V + (kh << 7);
    int b = bt >> 11, t = bt & 2047;
    dst = KVb + ((size_t)(b * KVH_ + kh) * T_ + t) * 256 + 128;
    donorm = 0;
  }
  u32 raw = ((const u32*)src)[lane];
  float x0 = b2f((u16)raw), x1 = b2f((u16)(raw >> 16));
  if (donorm) {
    float ss = x0 * x0 + x1 * x1;
    ss += __shfl_xor(ss, 1);  ss += __shfl_xor(ss, 2);  ss += __shfl_xor(ss, 4);
    ss += __shfl_xor(ss, 8);  ss += __shfl_xor(ss, 16); ss += __shfl_xor(ss, 32);
    float sc = extra / sqrtf(ss + 1e-6f);
    x0 *= sc; x1 *= sc;
  }
  f32x2 o; o.x = x0; o.y = x1;
  ((f32x2*)dst)[lane] = o;
}

// ---------------- per-(b,h,t): eg = exp(g), beta ----------------
__global__ __launch_bounds__(256) void eb_k(const u16* __restrict__ gba,
                                            const float* __restrict__ A_log,
                                            const float* __restrict__ dt_bias,
                                            f32x2* __restrict__ EB) {
  int i = blockIdx.x * 256 + threadIdx.x;          // i = bt*32 + hh  (hh in lane -> coalesced reads)
  int hh = i & 31; int bt = i >> 5;
  int t = bt & 2047, b = bt >> 11;
  const u16* rowp = gba + (size_t)bt * NGBA;
  float braw = b2f(rowp[OFS_B2 + hh]);
  float araw = b2f(rowp[OFS_A2 + hh]);
  float beta = 2.0f / (1.0f + expf(-braw));
  float x = araw + dt_bias[hh];
  float sp = (x > 20.0f) ? x : log1pf(expf(x));
  float g = -expf(A_log[hh]) * sp;
  f32x2 e; e.x = expf(g); e.y = beta;
  EB[((size_t)(b * H_ + hh)) * T_ + t] = e;
}

// ---------------- gated delta rule scan (R4) ----------------
// One 64-lane wave per (b, h, 8-dv slice).  lane = dkq(8) + 8*dvl(8).
// Lane owns S[dkq*16 .. +16)[dv0+dvl] in 4 f32x4. dk-reduce = shfl_xor 1,2,4.
// Scalar decay: k.(e^g * S) = e^g * (k.S).
// Pipeline: kS for step t is computed at step t-1 (k_{t} . S_after(t-1)), so
// the kS_next and o_cur 3-stage shuffle chains interleave. Quad ring buffers
// give loads ~3-4 steps (>800 cyc) of lead time; sched_barrier(0) per step
// pins issue order so the compiler can't sink the prefetch (R3 failure mode).
__global__ __launch_bounds__(64) void scan_k(const float* __restrict__ Qb, const float* __restrict__ KVb,
                                             const f32x2* __restrict__ EB, float* __restrict__ O) {
  int idx = blockIdx.x;
  int head = idx & 63, dvg = idx >> 6;
  int b = head >> 5, hh = head & 31;
  int lane = threadIdx.x;
  int dkq = lane & 7, dvl = lane >> 3;
  int dv0 = dvg << 3;
  const f32x4* qp = (const f32x4*)(Qb + ((size_t)(b * H_ + hh) * T_) * 128) + (dkq << 2);
  const f32x4* kp = (const f32x4*)(KVb + ((size_t)(b * KVH_ + (hh >> 2)) * T_) * 256) + (dkq << 2);
  const float* vp = KVb + ((size_t)(b * KVH_ + (hh >> 2)) * T_) * 256 + 128 + dv0 + dvl;
  const f32x2* ep = EB + (size_t)(b * H_ + hh) * T_;
  float* op = O + (size_t)b * T_ * (H_ * 128) + hh * 128 + dv0 + dvl;

  f32x4 S[4] = {};
  f32x4 kb[4][4], qb[4][4];
  float vb[4]; f32x2 eb[4];
#pragma unroll
  for (int j = 0; j < 4; ++j) {
#pragma unroll
    for (int c = 0; c < 4; ++c) { kb[j][c] = kp[j * 64 + c]; qb[j][c] = qp[j * 32 + c]; }
    vb[j] = vp[(size_t)j * 256]; eb[j] = ep[j];
  }
  float kS = 0.0f;                                  // k_0 . S_init = 0
  for (int t = 0; t < T_; t += 4) {
#pragma unroll
    for (int j = 0; j < 4; ++j) {
      int tt = t + j;
      float eg = eb[j].x, beta = eb[j].y;
      float vadj = (vb[j] - eg * kS) * beta;
#pragma unroll
      for (int c = 0; c < 4; ++c) S[c] = S[c] * eg + kb[j][c] * vadj;
      const int jn = (j + 1) & 3;                   // slot holding k_{tt+1}
      f32x4 p4 = kb[jn][0] * S[0] + kb[jn][1] * S[1] + kb[jn][2] * S[2] + kb[jn][3] * S[3];
      f32x4 r4 = qb[j][0] * S[0] + qb[j][1] * S[1] + qb[j][2] * S[2] + qb[j][3] * S[3];
      // refill slot j with step tt+4 (issued ~3-4 steps before use)
      int nt = tt + 4; if (nt > T_ - 1) nt = T_ - 1;
#pragma unroll
      for (int c = 0; c < 4; ++c) { kb[j][c] = kp[(size_t)nt * 64 + c]; qb[j][c] = qp[(size_t)nt * 32 + c]; }
      vb[j] = vp[(size_t)nt * 256]; eb[j] = ep[nt];
      // interleaved dual 3-stage reduces (independent chains)
      float p = (p4.x + p4.y) + (p4.z + p4.w);
      float r = (r4.x + r4.y) + (r4.z + r4.w);
      p += __shfl_xor(p, 1);  r += __shfl_xor(r, 1);
      p += __shfl_xor(p, 2);  r += __shfl_xor(r, 2);
      p += __shfl_xor(p, 4);  r += __shfl_xor(r, 4);
      kS = p;                                       // = k_{tt+1} . S_after(tt)
      if (dkq == 0) op[(size_t)tt * (H_ * 128)] = r;   // o_tt
      __builtin_amdgcn_sched_barrier(0);            // pin per-step schedule
    }
  }
}

// ---------------- rmsnorm(o)*w * gate*sigmoid(gate) -> bf16 Xo ----------------
__global__ __launch_bounds__(256) void ew2_k(const float* __restrict__ O, const u16* __restrict__ gba,
                                             const float* __restrict__ w, u16* __restrict__ Xo) {
  int r = blockIdx.x * 4 + (threadIdx.x >> 6);     // r = (b*T+t)*H + h
  int lane = threadIdx.x & 63;
  f32x2 ov = ((const f32x2*)(O + (size_t)r * 128))[lane];
  float ss = ov.x * ov.x + ov.y * ov.y;
  ss += __shfl_xor(ss, 1);  ss += __shfl_xor(ss, 2);  ss += __shfl_xor(ss, 4);
  ss += __shfl_xor(ss, 8);  ss += __shfl_xor(ss, 16); ss += __shfl_xor(ss, 32);
  float rms = 1.0f / sqrtf(ss * (1.0f / 128.0f) + 1e-5f);
  f32x2 wv = ((const f32x2*)w)[lane];
  int hh = r & 31; size_t bt = (size_t)(r >> 5);
  u32 graw = ((const u32*)(gba + bt * NGBA + (hh << 7)))[lane];
  float g0 = b2f((u16)graw), g1 = b2f((u16)(graw >> 16));
  float y0 = ov.x * rms * wv.x * (g0 / (1.0f + expf(-g0)));
  float y1 = ov.y * rms * wv.y * (g1 / (1.0f + expf(-g1)));
  u32 pk = (u32)f2b(y0) | ((u32)f2b(y1) << 16);
  ((u32*)(Xo + bt * 4096 + (hh << 7)))[lane] = pk;
}

// ---------------------------------------------------------------------------
extern "C" void kernel_launch(void* const* d_in, const int* in_sizes, int n_in,
                              void* d_out, int out_size, void* d_ws, size_t ws_size,
                              hipStream_t stream) {
  const float* h    = (const float*)d_in[0];
  const float* Wq   = (const float*)d_in[1];
  const float* Wk   = (const float*)d_in[2];
  const float* Wv   = (const float*)d_in[3];
  const float* Wb   = (const float*)d_in[4];
  const float* Wa   = (const float*)d_in[5];
  const float* Wg   = (const float*)d_in[6];
  const float* Wo   = (const float*)d_in[7];
  const float* Alog = (const float*)d_in[8];
  const float* dtb  = (const float*)d_in[9];
  const float* onw  = (const float*)d_in[10];

  // ---- workspace layout with lifetime unions (total ~210 MiB) ----
  constexpr size_t SZ_X     = (size_t)M_ * HID_ * 2;            // 16 MiB   [cast .. projGEMM]
  constexpr size_t SZ_WALLT = (size_t)NALL * HID_ * 2;          // 40.5 MiB [transpose .. projGEMM]
  constexpr size_t SZ_WOT   = (size_t)HID_ * 4096 * 2;          // 16 MiB   [.. finalGEMM]
  constexpr size_t SZ_QKV   = (size_t)M_ * NQKV * 2;            // 48 MiB   [projGEMM .. ew1]
  constexpr size_t SZ_GBA   = (size_t)M_ * NGBA * 2;            // 33 MiB   [projGEMM .. ew2]
  constexpr size_t SZ_QB    = (size_t)B_ * H_ * T_ * 128 * 4;   // 64 MiB   [ew1 .. scan]
  constexpr size_t SZ_KVB   = (size_t)B_ * KVH_ * T_ * 256 * 4; // 32 MiB   [ew1 .. scan]
  constexpr size_t SZ_EB    = (size_t)B_ * H_ * T_ * 8;         // 1 MiB    [eb .. scan]
  constexpr size_t SZ_O     = (size_t)M_ * H_ * 128 * 4;        // 64 MiB   [scan .. ew2]
  constexpr size_t SZ_U1    = SZ_QB;                            // >= SZ_X+SZ_WALLT, >= SZ_XO
  constexpr size_t SZ_U2    = SZ_O;                             // >= SZ_QKV
  constexpr size_t NEED = SZ_U1 + SZ_WOT + SZ_GBA + SZ_U2 + SZ_KVB + SZ_EB;  // 220,200,960

  if (ws_size < NEED) {   // diagnostic fallback: sentinel output, never fault
    fill_k<<<dim3((out_size + 255) / 256), dim3(256), 0, stream>>>((float*)d_out, out_size, 12345.0f);
    return;
  }

  char* base   = (char*)d_ws;
  char* segU1  = base;                    // P1-2: X @ +0, Wallt @ +SZ_X; P3-4: Qb; P5-6: Xo
  char* segWot = segU1 + SZ_U1;
  char* segGBA = segWot + SZ_WOT;
  char* segU2  = segGBA + SZ_GBA;         // P2-3: qkv; P4-5: O
  char* segKVB = segU2 + SZ_U2;
  char* segEB  = segKVB + SZ_KVB;

  u16*   X     = (u16*)segU1;
  u16*   Wallt = (u16*)(segU1 + SZ_X);
  u16*   Wot   = (u16*)segWot;
  u16*   qkv   = (u16*)segU2;
  u16*   gba   = (u16*)segGBA;
  float* Qb    = (float*)segU1;
  float* KVb   = (float*)segKVB;
  f32x2* EB    = (f32x2*)segEB;
  float* O     = (float*)segU2;
  u16*   Xo    = (u16*)segU1;

  cast_bf16_k<<<dim3(M_ * HID_ / 4 / 256), dim3(256), 0, stream>>>(h, X, M_ * HID_ / 4);

  // Wallt rows: [0,4096)=Wq^T | [4096,5120)=Wk^T | [5120,6144)=Wv^T |
  //             [6144,10240)=Wg^T | [10240,10272)=Wb^T | [10272,10304)=Wa^T | [10304,10368)=0
  transpose_cast_k<<<dim3(4096/32, 2048/32), dim3(256), 0, stream>>>(Wq, Wallt, 2048, 4096);
  transpose_cast_k<<<dim3(1024/32, 2048/32), dim3(256), 0, stream>>>(Wk, Wallt + (size_t)4096 * HID_, 2048, 1024);
  transpose_cast_k<<<dim3(1024/32, 2048/32), dim3(256), 0, stream>>>(Wv, Wallt + (size_t)5120 * HID_, 2048, 1024);
  transpose_cast_k<<<dim3(4096/32, 2048/32), dim3(256), 0, stream>>>(Wg, Wallt + (size_t)6144 * HID_, 2048, 4096);
  transpose_cast_k<<<dim3(32/32,   2048/32), dim3(256), 0, stream>>>(Wb, Wallt + (size_t)10240 * HID_, 2048, 32);
  transpose_cast_k<<<dim3(32/32,   2048/32), dim3(256), 0, stream>>>(Wa, Wallt + (size_t)10272 * HID_, 2048, 32);
  hipMemsetAsync(Wallt + (size_t)10304 * HID_, 0, (size_t)64 * HID_ * 2, stream);
  transpose_cast_k<<<dim3(2048/32, 4096/32), dim3(256), 0, stream>>>(Wo, Wot, 4096, 2048);

  // projection GEMMs (bf16 out)
  gemm_nt_k<1><<<dim3(NQKV/128, M_/128), dim3(256), 0, stream>>>(X, Wallt, qkv, M_, NQKV, HID_);
  gemm_nt_k<1><<<dim3(NGBA/128, M_/128), dim3(256), 0, stream>>>(X, Wallt + (size_t)NQKV * HID_, gba, M_, NGBA, HID_);

  ew1_k<<<dim3((B_*T_*H_ + 2*B_*T_*KVH_) / 4), dim3(256), 0, stream>>>(qkv, Qb, KVb);
  eb_k<<<dim3(B_*H_*T_ / 256), dim3(256), 0, stream>>>(gba, Alog, dtb, EB);

  scan_k<<<dim3(B_*H_ * 16), dim3(64), 0, stream>>>(Qb, KVb, EB, O);

  ew2_k<<<dim3(B_*T_*H_ / 4), dim3(256), 0, stream>>>(O, gba, onw, Xo);

  // output projection: d_out[4096][2048] = Xo @ Wo  (Wot is Wo^T, fp32 out)
  gemm_nt_k<0><<<dim3(2048/128, M_/128), dim3(256), 0, stream>>>(Xo, Wot, d_out, M_, 2048, 4096);
}